// Round 6
// baseline (160.777 us; speedup 1.0000x reference)
//
#include <hip/hip_runtime.h>

#define C_CH  256
#define H_FM  200
#define W_FM  200
#define N_BOX 1024
#define OHp   7
#define OWp   7
#define NG    8                       // channel groups
#define CG    32                      // channels per group
#define WC    (W_FM * C_CH)           // 51200 columns
#define NCHUNK 25                     // h chunks of 8 rows
#define CHROWS 8
#define GSTRIDE (H_FM * W_FM * CG)    // 1,280,000 floats per group slice
#define HSTRIDE (W_FM * CG)           // 6,400 floats per h row (within group)
#define AUXG    (NCHUNK * HSTRIDE)    // 160,000 floats per group aux slice

// ============================================================================
// Layouts:
//   T2[g][h][w][cg]   : w-scanned, h-scanned WITHIN 8-row chunks.
//   aux2[g][ch][w][cg]: exclusive h-chunk offsets (after aux_scan).
// Final integral image (1-based r,k):
//   II(r,k)[c] = T2[g][r-1][k-1][cg] + aux2[g][(r-1)>>3][k-1][cg];  II(0,*)=II(*,0)=0
// ============================================================================

// ----------------------------------------------------------------------------
// K1: FUSED transpose + w-scan + chunk h-scan. Block = (h-chunk, g).
// Streams 8 h rows: float4 coalesced load -> LDS w-scan (register-serial per
// 25-wide chunk + LDS offset fixup) -> add running chunk accumulator (held in
// 7 float4 regs/thread) -> float4 coalesced store. Final acc -> aux2.
// Replaces the separate colscan pass (saves 82 MB of traffic).
// ----------------------------------------------------------------------------
__global__ __launch_bounds__(256) void fused_scan_kernel(const float* __restrict__ fm,
                                                         float* __restrict__ T2,
                                                         float* __restrict__ aux2) {
    __shared__ float tile[W_FM][CG + 1];   // [w][cg], +1 pad
    __shared__ float tot[8][CG + 1];
    __shared__ float offE[8][CG + 1];
    const int t   = threadIdx.x;
    const int chk = blockIdx.x;            // 0..24
    const int g   = blockIdx.y;            // 0..7
    const int c0  = g * CG;
    const int h0  = chk * CHROWS;
    const int cg  = t & 31;
    const int chb = t >> 5;                // 0..7

    float4 acc[7];
    #pragma unroll
    for (int u = 0; u < 7; ++u) acc[u] = make_float4(0.f, 0.f, 0.f, 0.f);

    const float* srcBase = fm + (size_t)c0 * (H_FM * W_FM);
    float* dstBase = T2 + (size_t)g * GSTRIDE;

    for (int hh = 0; hh < CHROWS; ++hh) {
        const int h = h0 + hh;
        // (a) coalesced float4 load of 32 channel-rows x 200 w (1600 float4)
        const float* src = srcBase + (size_t)h * W_FM;
        #pragma unroll
        for (int it = 0; it < 7; ++it) {
            int item = it * 256 + t;
            if (item < 1600) {
                int ci = item / 50;
                int w4 = item - ci * 50;
                float4 v = *(const float4*)(src + (size_t)ci * (H_FM * W_FM) + w4 * 4);
                tile[w4 * 4 + 0][ci] = v.x;
                tile[w4 * 4 + 1][ci] = v.y;
                tile[w4 * 4 + 2][ci] = v.z;
                tile[w4 * 4 + 3][ci] = v.w;
            }
        }
        __syncthreads();
        // (b) register-serial w-scan of 25-wide chunk
        {
            float a = 0.f;
            #pragma unroll
            for (int s = 0; s < 25; ++s) {
                a += tile[chb * 25 + s][cg];
                tile[chb * 25 + s][cg] = a;
            }
            tot[chb][cg] = a;
        }
        __syncthreads();
        // (c) exclusive scan of the 8 w-chunk totals
        {
            float off = 0.f;
            #pragma unroll
            for (int k = 0; k < 8; ++k) {
                float v = tot[k][cg];
                if (k < chb) off += v;
            }
            offE[chb][cg] = off;
        }
        __syncthreads();
        // (d) add chunk accumulator, float4 coalesced store of finalized row
        float* dst = dstBase + (size_t)h * HSTRIDE;
        #pragma unroll
        for (int it = 0; it < 7; ++it) {
            int f4 = it * 256 + t;
            if (f4 < 1600) {
                int w  = f4 >> 3;
                int cc = (f4 & 7) * 4;
                int wb = w / 25;
                float4 v;
                v.x = tile[w][cc + 0] + offE[wb][cc + 0] + acc[it].x;
                v.y = tile[w][cc + 1] + offE[wb][cc + 1] + acc[it].y;
                v.z = tile[w][cc + 2] + offE[wb][cc + 2] + acc[it].z;
                v.w = tile[w][cc + 3] + offE[wb][cc + 3] + acc[it].w;
                acc[it] = v;
                *(float4*)(dst + (size_t)f4 * 4) = v;
            }
        }
        __syncthreads();   // tile/tot/offE reuse next row
    }
    // chunk totals -> aux2[g][chk]
    float* adst = aux2 + (size_t)g * AUXG + (size_t)chk * HSTRIDE;
    #pragma unroll
    for (int it = 0; it < 7; ++it) {
        int f4 = it * 256 + t;
        if (f4 < 1600) *(float4*)(adst + (size_t)f4 * 4) = acc[it];
    }
}

// ----------------------------------------------------------------------------
// K2: exclusive scan of the 25 chunk totals, in place, float4.
// 64-thread blocks x 200 -> covers 200 CUs (was 50 blocks).
// ----------------------------------------------------------------------------
__global__ __launch_bounds__(64) void aux_scan_kernel(float* __restrict__ aux2) {
    const int idx = blockIdx.x * 64 + threadIdx.x;    // 0..WC/4-1
    const int g   = idx / (HSTRIDE / 4);
    const int r4  = idx - g * (HSTRIDE / 4);
    float4* p = (float4*)aux2 + (size_t)g * (AUXG / 4) + r4;
    float4 acc = make_float4(0.f, 0.f, 0.f, 0.f);
    #pragma unroll
    for (int ch = 0; ch < NCHUNK; ++ch) {
        float4 v = p[(size_t)ch * (HSTRIDE / 4)];
        p[(size_t)ch * (HSTRIDE / 4)] = acc;
        acc.x += v.x; acc.y += v.y; acc.z += v.z; acc.w += v.w;
    }
}

// ----------------------------------------------------------------------------
// K3: pooling via a 14x14 corner grid in LDS.
// Block = (box n, group g), blockIdx = n*8+g (XCD slicing).
// Phase 1: load the 196 unique II corner positions x 32 ch as float4
//   (8 lanes x 16 B per position -> one 128 B segment each; T2+aux summed at
//   load). ~25+25 VMEM wave-instrs/block vs pool5's 196.
// Phase 2: thread (cg, islot<7) computes 7 bins from LDS grid; staged in lo,
//   float4 coalesced flush.
// ----------------------------------------------------------------------------
__global__ __launch_bounds__(256) void pool6_kernel(const float* __restrict__ T2,
                                                    const float* __restrict__ aux2,
                                                    const float* __restrict__ boxes,
                                                    float* __restrict__ out) {
    __shared__ __align__(16) float grid[196][36];   // [pos][cg], stride 36 (16B-mult)
    __shared__ __align__(16) float lo[CG * 49];
    const int bx = blockIdx.x;
    const int n  = bx >> 3;
    const int g  = bx & 7;
    const int t  = threadIdx.x;

    const float4 box = ((const float4*)boxes)[n];
    int b0 = (int)floorf(box.x * 0.25f);
    int b1 = (int)floorf(box.y * 0.25f);
    int b2 = (int)floorf(box.z * 0.25f);
    int b3 = (int)floorf(box.w * 0.25f);
    int x1 = min(max(b0, 0), W_FM - 1);
    int y1 = min(max(b1, 0), H_FM - 1);
    int x2 = min(max(b2 + 1, x1 + 1), W_FM);
    int y2 = min(max(b3 + 1, y1 + 1), H_FM);
    int rh = y2 - y1;
    int rw = x2 - x1;

    // ---- phase 1: grid load. pos = ri*14+ci; ri<7 -> rs[ri], ri>=7 -> re[ri-7]
    {
        const int c4 = t & 7;              // float4 lane within 32 channels
        const int p0 = t >> 3;             // 0..31 positions per iteration
        const float* Tg = T2   + (size_t)g * GSTRIDE + c4 * 4;
        const float* Ag = aux2 + (size_t)g * AUXG   + c4 * 4;
        #pragma unroll
        for (int it = 0; it < 7; ++it) {
            int pos = it * 32 + p0;
            if (pos < 196) {
                int ri = pos / 14;
                int ci = pos - ri * 14;
                int r = (ri < 7) ? (y1 + (ri * rh) / OHp)
                                 : (y1 + ((ri - 6) * rh + OHp - 1) / OHp);
                int k = (ci < 7) ? (x1 + (ci * rw) / OWp)
                                 : (x1 + ((ci - 6) * rw + OWp - 1) / OWp);
                float4 v = make_float4(0.f, 0.f, 0.f, 0.f);
                if (r > 0 && k > 0) {
                    float4 tv = *(const float4*)(Tg + ((size_t)(r - 1) * W_FM + (k - 1)) * CG);
                    float4 av = *(const float4*)(Ag + ((size_t)((r - 1) >> 3) * W_FM + (k - 1)) * CG);
                    v.x = tv.x + av.x; v.y = tv.y + av.y;
                    v.z = tv.z + av.z; v.w = tv.w + av.w;
                }
                *(float4*)&grid[pos][c4 * 4] = v;
            }
        }
    }
    __syncthreads();

    // ---- phase 2: bin math from LDS
    {
        const int cg = t & 31;
        const int islot = t >> 5;          // 0..7 (7 idle)
        if (islot < OHp) {
            const int i  = islot;
            const int rt = y1 + (i * rh) / OHp;
            const int rb = y1 + ((i + 1) * rh + OHp - 1) / OHp;
            const float rowspan = (float)(rb - rt);
            #pragma unroll
            for (int j = 0; j < OWp; ++j) {
                const int csj = x1 + (j * rw) / OWp;
                const int cej = x1 + ((j + 1) * rw + OWp - 1) / OWp;
                float a = grid[(7 + i) * 14 + 7 + j][cg];   // II(re, ce)
                float b = grid[i * 14 + 7 + j][cg];         // II(rs, ce)
                float c = grid[(7 + i) * 14 + j][cg];       // II(re, cs)
                float d = grid[i * 14 + j][cg];             // II(rs, cs)
                float total = (a - b) - (c - d);
                float area  = rowspan * (float)(cej - csj);
                lo[cg * 49 + i * OWp + j] = total / area;
            }
        }
    }
    __syncthreads();

    // ---- float4 flush: 392 float4 = 1568 contiguous floats
    float4* dst4 = (float4*)(out + (size_t)n * (C_CH * 49) + (size_t)g * (CG * 49));
    const float4* lo4 = (const float4*)lo;
    #pragma unroll
    for (int m = 0; m < 2; ++m) {
        int idx = m * 256 + t;
        if (idx < CG * 49 / 4) dst4[idx] = lo4[idx];
    }
}

// ============================================================================
// FALLBACK PATH — used only if workspace is too small.
// ============================================================================
__device__ __forceinline__ void box_edges(const float4 box, int i, int j,
                                          int& rs, int& re, int& cs, int& ce) {
    int b0 = (int)floorf(box.x * 0.25f);
    int b1 = (int)floorf(box.y * 0.25f);
    int b2 = (int)floorf(box.z * 0.25f);
    int b3 = (int)floorf(box.w * 0.25f);
    int x1 = min(max(b0, 0), W_FM - 1);
    int y1 = min(max(b1, 0), H_FM - 1);
    int x2 = min(max(b2 + 1, x1 + 1), W_FM);
    int y2 = min(max(b3 + 1, y1 + 1), H_FM);
    int rh = y2 - y1;
    int rw = x2 - x1;
    rs = y1 + (i * rh) / OHp;
    re = y1 + ((i + 1) * rh + OHp - 1) / OHp;
    cs = x1 + (j * rw) / OWp;
    ce = x1 + ((j + 1) * rw + OWp - 1) / OWp;
}

__global__ __launch_bounds__(256) void pool_direct_kernel(const float* __restrict__ fm,
                                                          const float* __restrict__ boxes,
                                                          float* __restrict__ out) {
    const int idx = blockIdx.x * 256 + threadIdx.x;
    const int j  = idx % OWp;
    const int t1 = idx / OWp;
    const int i  = t1 % OHp;
    const int t2 = t1 / OHp;
    const int c  = t2 % C_CH;
    const int n  = t2 / C_CH;

    const float4 box = ((const float4*)boxes)[n];
    int rs, re, cs, ce;
    box_edges(box, i, j, rs, re, cs, ce);

    const float* base = fm + (size_t)c * (H_FM * W_FM);
    float sum = 0.0f;
    for (int r = rs; r < re; ++r) {
        const float* rowp = base + (size_t)r * W_FM;
        for (int k = cs; k < ce; ++k) sum += rowp[k];
    }
    float area = (float)((re - rs) * (ce - cs));
    out[idx] = sum / area;
}

// ---------------------------------------------------------------------------
extern "C" void kernel_launch(void* const* d_in, const int* in_sizes, int n_in,
                              void* d_out, int out_size, void* d_ws, size_t ws_size,
                              hipStream_t stream) {
    const float* fm    = (const float*)d_in[0];   // [1,256,200,200] f32
    const float* boxes = (const float*)d_in[1];   // [1024,4] f32
    float* out = (float*)d_out;                   // [1024,256,7,7] f32

    const size_t tBytes   = (size_t)NG * GSTRIDE * sizeof(float);     // 40.96 MB
    const size_t auxBytes = (size_t)NG * AUXG * sizeof(float);        // 5.12 MB
    const int    total    = N_BOX * C_CH * OHp * OWp;
    const int    blocks   = total / 256;

    if (ws_size >= tBytes + auxBytes) {
        float* T2   = (float*)d_ws;
        float* aux2 = (float*)((char*)d_ws + tBytes);
        fused_scan_kernel<<<dim3(NCHUNK, NG), 256, 0, stream>>>(fm, T2, aux2);
        aux_scan_kernel<<<WC / 4 / 64, 64, 0, stream>>>(aux2);
        pool6_kernel<<<N_BOX * NG, 256, 0, stream>>>(T2, aux2, boxes, out);
    } else {
        pool_direct_kernel<<<blocks, 256, 0, stream>>>(fm, boxes, out);
    }
}

// Round 7
// 146.056 us; speedup vs baseline: 1.1008x; 1.1008x over previous
//
#include <hip/hip_runtime.h>

#define C_CH  256
#define H_FM  200
#define W_FM  200
#define N_BOX 1024
#define OHp   7
#define OWp   7
#define NG    8                       // channel groups
#define CG    32                      // channels per group
#define WC    (W_FM * C_CH)           // 51200 columns
#define NCHUNK 25                     // h chunks of 8 rows
#define CHROWS 8
#define GSTRIDE (H_FM * W_FM * CG)    // 1,280,000 floats per group slice
#define HSTRIDE (W_FM * CG)           // 6,400 floats per h row (within group)
#define AUXG    (NCHUNK * HSTRIDE)    // 160,000 floats per group aux slice

// ============================================================================
// Layouts:
//   T2[g][h][w][cg]   : w-scanned, h-scanned WITHIN 8-row chunks.
//   aux2[g][ch][w][cg]: exclusive h-chunk offsets (after aux_scan).
// Final integral image (1-based r,k):
//   II(r,k)[c] = T2[g][r-1][k-1][cg] + aux2[g][(r-1)>>3][k-1][cg];  II(0,*)=0
// ============================================================================

// ----------------------------------------------------------------------------
// K1 (R5-proven): coalesced scalar load -> LDS (stride-33, conflict-free) ->
// register-serial w-scan -> coalesced transposed store. Block = (h, g).
// ----------------------------------------------------------------------------
__global__ __launch_bounds__(256) void transpose_wscan_kernel(const float* __restrict__ fm,
                                                              float* __restrict__ T2) {
    __shared__ float tile[W_FM][CG + 1];   // [w][cg]
    __shared__ float tot[8][CG + 1];
    __shared__ float offE[8][CG + 1];
    const int t = threadIdx.x;
    const int h = blockIdx.x;
    const int g = blockIdx.y;
    const int c0 = g * CG;

    #pragma unroll
    for (int s = 0; s < 25; ++s) {
        int flat = s * 256 + t;            // 0..6399
        int ci = flat / W_FM;
        int w  = flat - ci * W_FM;
        tile[w][ci] = fm[(size_t)(c0 + ci) * (H_FM * W_FM) + (size_t)h * W_FM + w];
    }
    __syncthreads();

    const int cg  = t & 31;
    const int chb = t >> 5;                // 0..7
    {
        float acc = 0.0f;
        #pragma unroll
        for (int s = 0; s < 25; ++s) {
            acc += tile[chb * 25 + s][cg];
            tile[chb * 25 + s][cg] = acc;
        }
        tot[chb][cg] = acc;
    }
    __syncthreads();

    {
        float off = 0.0f;
        #pragma unroll
        for (int k = 0; k < 8; ++k) {
            float v = tot[k][cg];
            if (k < chb) off += v;
        }
        offE[chb][cg] = off;
    }
    __syncthreads();

    float* dst = T2 + (size_t)g * GSTRIDE + (size_t)h * HSTRIDE;
    #pragma unroll
    for (int m = 0; m < 25; ++m) {
        int flat = m * 256 + t;
        int w  = flat >> 5;
        int cc = flat & 31;
        dst[flat] = tile[w][cc] + offE[w / 25][cc];
    }
}

// ----------------------------------------------------------------------------
// K2 (R5-proven): h-cumsum per chunk of 8 rows, in place, float4. Chunk totals
// to aux2[g][ch]. Grid (50, 25). Fully coalesced 16 B/lane.
// ----------------------------------------------------------------------------
__global__ __launch_bounds__(256) void colscan_chunk_kernel(float* __restrict__ T2,
                                                            float* __restrict__ aux2) {
    const int q4 = blockIdx.x * 256 + threadIdx.x;    // 0..WC/4-1
    const int ch = blockIdx.y;
    const int g  = q4 / (HSTRIDE / 4);
    const int r4 = q4 - g * (HSTRIDE / 4);
    float4* p = (float4*)T2 + (size_t)g * (GSTRIDE / 4)
                            + (size_t)(ch * CHROWS) * (HSTRIDE / 4) + r4;
    float4 acc = make_float4(0.f, 0.f, 0.f, 0.f);
    #pragma unroll
    for (int k = 0; k < CHROWS; ++k) {
        float4 v = p[(size_t)k * (HSTRIDE / 4)];
        acc.x += v.x; acc.y += v.y; acc.z += v.z; acc.w += v.w;
        p[(size_t)k * (HSTRIDE / 4)] = acc;
    }
    ((float4*)aux2)[(size_t)g * (AUXG / 4) + (size_t)ch * (HSTRIDE / 4) + r4] = acc;
}

// ----------------------------------------------------------------------------
// K3: exclusive scan of the 25 chunk totals, in place, float4. 200 blocks.
// ----------------------------------------------------------------------------
__global__ __launch_bounds__(64) void aux_scan_kernel(float* __restrict__ aux2) {
    const int idx = blockIdx.x * 64 + threadIdx.x;    // 0..WC/4-1
    const int g   = idx / (HSTRIDE / 4);
    const int r4  = idx - g * (HSTRIDE / 4);
    float4* p = (float4*)aux2 + (size_t)g * (AUXG / 4) + r4;
    float4 acc = make_float4(0.f, 0.f, 0.f, 0.f);
    #pragma unroll
    for (int ch = 0; ch < NCHUNK; ++ch) {
        float4 v = p[(size_t)ch * (HSTRIDE / 4)];
        p[(size_t)ch * (HSTRIDE / 4)] = acc;
        acc.x += v.x; acc.y += v.y; acc.z += v.z; acc.w += v.w;
    }
}

// ----------------------------------------------------------------------------
// K4: pool7 = pool6 grid-dedup + LDS-hoisted edges.
// 28 edge values (er[14]: rs0..6,re0..6; ec[14]: cs0..6,ce0..6) computed ONCE
// by two waves, then phases read them from LDS (broadcast-pattern ds_read) —
// no per-thread division chains.
// Phase 1: 196 positions x 32ch as float4 (8 lanes/pos), T2+aux summed.
// Phase 2: bin math from LDS grid; float4 coalesced flush.
// ----------------------------------------------------------------------------
__global__ __launch_bounds__(256) void pool7_kernel(const float* __restrict__ T2,
                                                    const float* __restrict__ aux2,
                                                    const float* __restrict__ boxes,
                                                    float* __restrict__ out) {
    __shared__ __align__(16) float grid[196][36];   // [pos][cg], stride 36
    __shared__ __align__(16) float lo[CG * 49];
    __shared__ int er[14];                          // rows: rs[0..6], re[0..6]
    __shared__ int ec[14];                          // cols: cs[0..6], ce[0..6]
    const int bx = blockIdx.x;
    const int n  = bx >> 3;
    const int g  = bx & 7;
    const int t  = threadIdx.x;

    const float4 box = ((const float4*)boxes)[n];
    int b0 = (int)floorf(box.x * 0.25f);
    int b1 = (int)floorf(box.y * 0.25f);
    int b2 = (int)floorf(box.z * 0.25f);
    int b3 = (int)floorf(box.w * 0.25f);
    int x1 = min(max(b0, 0), W_FM - 1);
    int y1 = min(max(b1, 0), H_FM - 1);
    int x2 = min(max(b2 + 1, x1 + 1), W_FM);
    int y2 = min(max(b3 + 1, y1 + 1), H_FM);
    int rh = y2 - y1;
    int rw = x2 - x1;

    // ---- edge precompute: wave 0 lanes 0..13 do rows, wave 1 lanes 0..13 cols
    if (t < 14) {
        er[t] = (t < 7) ? (y1 + (t * rh) / OHp)
                        : (y1 + ((t - 6) * rh + OHp - 1) / OHp);
    } else if (t >= 64 && t < 78) {
        int u = t - 64;
        ec[u] = (u < 7) ? (x1 + (u * rw) / OWp)
                        : (x1 + ((u - 6) * rw + OWp - 1) / OWp);
    }
    __syncthreads();

    // ---- phase 1: grid load (positions deduped; edges from LDS)
    {
        const int c4 = t & 7;              // float4 slot within 32 channels
        const int p0 = t >> 3;             // 0..31 positions per iteration
        const float* Tg = T2   + (size_t)g * GSTRIDE + c4 * 4;
        const float* Ag = aux2 + (size_t)g * AUXG   + c4 * 4;
        #pragma unroll
        for (int it = 0; it < 7; ++it) {
            int pos = it * 32 + p0;
            if (pos < 196) {
                int ri = pos / 14;
                int ci = pos - ri * 14;
                int r = er[ri];
                int k = ec[ci];
                float4 v = make_float4(0.f, 0.f, 0.f, 0.f);
                if (r > 0 && k > 0) {
                    float4 tv = *(const float4*)(Tg + ((size_t)(r - 1) * W_FM + (k - 1)) * CG);
                    float4 av = *(const float4*)(Ag + ((size_t)((r - 1) >> 3) * W_FM + (k - 1)) * CG);
                    v.x = tv.x + av.x; v.y = tv.y + av.y;
                    v.z = tv.z + av.z; v.w = tv.w + av.w;
                }
                *(float4*)&grid[pos][c4 * 4] = v;
            }
        }
    }
    __syncthreads();

    // ---- phase 2: bin math from LDS (edges from LDS, no divisions)
    {
        const int cg = t & 31;
        const int islot = t >> 5;          // 0..7 (7 idle)
        if (islot < OHp) {
            const int i  = islot;
            const float rowspan = (float)(er[7 + i] - er[i]);
            #pragma unroll
            for (int j = 0; j < OWp; ++j) {
                float a = grid[(7 + i) * 14 + 7 + j][cg];   // II(re, ce)
                float b = grid[i * 14 + 7 + j][cg];         // II(rs, ce)
                float c = grid[(7 + i) * 14 + j][cg];       // II(re, cs)
                float d = grid[i * 14 + j][cg];             // II(rs, cs)
                float total = (a - b) - (c - d);
                float area  = rowspan * (float)(ec[7 + j] - ec[j]);
                lo[cg * 49 + i * OWp + j] = total / area;
            }
        }
    }
    __syncthreads();

    // ---- float4 flush: 392 float4 = 1568 contiguous floats
    float4* dst4 = (float4*)(out + (size_t)n * (C_CH * 49) + (size_t)g * (CG * 49));
    const float4* lo4 = (const float4*)lo;
    #pragma unroll
    for (int m = 0; m < 2; ++m) {
        int idx = m * 256 + t;
        if (idx < CG * 49 / 4) dst4[idx] = lo4[idx];
    }
}

// ============================================================================
// FALLBACK PATH — used only if workspace is too small.
// ============================================================================
__device__ __forceinline__ void box_edges(const float4 box, int i, int j,
                                          int& rs, int& re, int& cs, int& ce) {
    int b0 = (int)floorf(box.x * 0.25f);
    int b1 = (int)floorf(box.y * 0.25f);
    int b2 = (int)floorf(box.z * 0.25f);
    int b3 = (int)floorf(box.w * 0.25f);
    int x1 = min(max(b0, 0), W_FM - 1);
    int y1 = min(max(b1, 0), H_FM - 1);
    int x2 = min(max(b2 + 1, x1 + 1), W_FM);
    int y2 = min(max(b3 + 1, y1 + 1), H_FM);
    int rh = y2 - y1;
    int rw = x2 - x1;
    rs = y1 + (i * rh) / OHp;
    re = y1 + ((i + 1) * rh + OHp - 1) / OHp;
    cs = x1 + (j * rw) / OWp;
    ce = x1 + ((j + 1) * rw + OWp - 1) / OWp;
}

__global__ __launch_bounds__(256) void pool_direct_kernel(const float* __restrict__ fm,
                                                          const float* __restrict__ boxes,
                                                          float* __restrict__ out) {
    const int idx = blockIdx.x * 256 + threadIdx.x;
    const int j  = idx % OWp;
    const int t1 = idx / OWp;
    const int i  = t1 % OHp;
    const int t2 = t1 / OHp;
    const int c  = t2 % C_CH;
    const int n  = t2 / C_CH;

    const float4 box = ((const float4*)boxes)[n];
    int rs, re, cs, ce;
    box_edges(box, i, j, rs, re, cs, ce);

    const float* base = fm + (size_t)c * (H_FM * W_FM);
    float sum = 0.0f;
    for (int r = rs; r < re; ++r) {
        const float* rowp = base + (size_t)r * W_FM;
        for (int k = cs; k < ce; ++k) sum += rowp[k];
    }
    float area = (float)((re - rs) * (ce - cs));
    out[idx] = sum / area;
}

// ---------------------------------------------------------------------------
extern "C" void kernel_launch(void* const* d_in, const int* in_sizes, int n_in,
                              void* d_out, int out_size, void* d_ws, size_t ws_size,
                              hipStream_t stream) {
    const float* fm    = (const float*)d_in[0];   // [1,256,200,200] f32
    const float* boxes = (const float*)d_in[1];   // [1024,4] f32
    float* out = (float*)d_out;                   // [1024,256,7,7] f32

    const size_t tBytes   = (size_t)NG * GSTRIDE * sizeof(float);     // 40.96 MB
    const size_t auxBytes = (size_t)NG * AUXG * sizeof(float);        // 5.12 MB
    const int    total    = N_BOX * C_CH * OHp * OWp;
    const int    blocks   = total / 256;

    if (ws_size >= tBytes + auxBytes) {
        float* T2   = (float*)d_ws;
        float* aux2 = (float*)((char*)d_ws + tBytes);
        transpose_wscan_kernel<<<dim3(H_FM, NG), 256, 0, stream>>>(fm, T2);
        colscan_chunk_kernel<<<dim3(WC / 4 / 256, NCHUNK), 256, 0, stream>>>(T2, aux2);
        aux_scan_kernel<<<WC / 4 / 64, 64, 0, stream>>>(aux2);
        pool7_kernel<<<N_BOX * NG, 256, 0, stream>>>(T2, aux2, boxes, out);
    } else {
        pool_direct_kernel<<<blocks, 256, 0, stream>>>(fm, boxes, out);
    }
}

// Round 8
// 139.633 us; speedup vs baseline: 1.1514x; 1.0460x over previous
//
#include <hip/hip_runtime.h>

#define C_CH  256
#define H_FM  200
#define W_FM  200
#define N_BOX 1024
#define OHp   7
#define OWp   7
#define NG    8                       // channel groups
#define CG    32                      // channels per group
#define WC    (W_FM * C_CH)           // 51200 columns
#define NCHUNK 25                     // h chunks of 8 rows
#define CHROWS 8
#define GSTRIDE (H_FM * W_FM * CG)    // 1,280,000 floats per group slice
#define HSTRIDE (W_FM * CG)           // 6,400 floats per h row (within group)
#define AUXG    (NCHUNK * HSTRIDE)    // 160,000 floats per group aux slice
#define GPAD  33                      // grid LDS stride (floats)

// ============================================================================
// Layouts:
//   T2[g][h][w][cg]   : w-scanned, h-scanned WITHIN 8-row chunks.
//   aux2[g][ch][w][cg]: exclusive h-chunk offsets (after aux_scan).
// Final integral image (1-based r,k):
//   II(r,k)[c] = T2[g][r-1][k-1][cg] + aux2[g][(r-1)>>3][k-1][cg];  II(0,*)=0
// ============================================================================

// ----------------------------------------------------------------------------
// K1: coalesced scalar load -> LDS (stride-33, conflict-free) -> register-
// serial w-scan -> float4 coalesced transposed store (offE folded).
// Block = (h, g).
// ----------------------------------------------------------------------------
__global__ __launch_bounds__(256) void transpose_wscan_kernel(const float* __restrict__ fm,
                                                              float* __restrict__ T2) {
    __shared__ float tile[W_FM][CG + 1];   // [w][cg]
    __shared__ float tot[8][CG + 1];
    __shared__ float offE[8][CG + 1];
    const int t = threadIdx.x;
    const int h = blockIdx.x;
    const int g = blockIdx.y;
    const int c0 = g * CG;

    #pragma unroll
    for (int s = 0; s < 25; ++s) {
        int flat = s * 256 + t;            // 0..6399
        int ci = flat / W_FM;
        int w  = flat - ci * W_FM;
        tile[w][ci] = fm[(size_t)(c0 + ci) * (H_FM * W_FM) + (size_t)h * W_FM + w];
    }
    __syncthreads();

    const int cg  = t & 31;
    const int chb = t >> 5;                // 0..7
    {
        float acc = 0.0f;
        #pragma unroll
        for (int s = 0; s < 25; ++s) {
            acc += tile[chb * 25 + s][cg];
            tile[chb * 25 + s][cg] = acc;
        }
        tot[chb][cg] = acc;
    }
    __syncthreads();

    {
        float off = 0.0f;
        #pragma unroll
        for (int k = 0; k < 8; ++k) {
            float v = tot[k][cg];
            if (k < chb) off += v;
        }
        offE[chb][cg] = off;
    }
    __syncthreads();

    // float4 store: 1600 float4 per block; LDS read banks (w+4c4+k)%32 = 2-way
    float* dst = T2 + (size_t)g * GSTRIDE + (size_t)h * HSTRIDE;
    #pragma unroll
    for (int it = 0; it < 7; ++it) {
        int f4 = it * 256 + t;
        if (f4 < 1600) {
            int w  = f4 >> 3;
            int cc = (f4 & 7) * 4;
            int wb = w / 25;
            float4 v;
            v.x = tile[w][cc + 0] + offE[wb][cc + 0];
            v.y = tile[w][cc + 1] + offE[wb][cc + 1];
            v.z = tile[w][cc + 2] + offE[wb][cc + 2];
            v.w = tile[w][cc + 3] + offE[wb][cc + 3];
            *(float4*)(dst + (size_t)f4 * 4) = v;
        }
    }
}

// ----------------------------------------------------------------------------
// K2 (roofline): h-cumsum per chunk of 8 rows, in place, float4. Chunk totals
// to aux2[g][ch]. Grid (50, 25). Fully coalesced 16 B/lane.
// ----------------------------------------------------------------------------
__global__ __launch_bounds__(256) void colscan_chunk_kernel(float* __restrict__ T2,
                                                            float* __restrict__ aux2) {
    const int q4 = blockIdx.x * 256 + threadIdx.x;    // 0..WC/4-1
    const int ch = blockIdx.y;
    const int g  = q4 / (HSTRIDE / 4);
    const int r4 = q4 - g * (HSTRIDE / 4);
    float4* p = (float4*)T2 + (size_t)g * (GSTRIDE / 4)
                            + (size_t)(ch * CHROWS) * (HSTRIDE / 4) + r4;
    float4 acc = make_float4(0.f, 0.f, 0.f, 0.f);
    #pragma unroll
    for (int k = 0; k < CHROWS; ++k) {
        float4 v = p[(size_t)k * (HSTRIDE / 4)];
        acc.x += v.x; acc.y += v.y; acc.z += v.z; acc.w += v.w;
        p[(size_t)k * (HSTRIDE / 4)] = acc;
    }
    ((float4*)aux2)[(size_t)g * (AUXG / 4) + (size_t)ch * (HSTRIDE / 4) + r4] = acc;
}

// ----------------------------------------------------------------------------
// K3: exclusive scan of the 25 chunk totals, in place, float4. 200 blocks.
// ----------------------------------------------------------------------------
__global__ __launch_bounds__(64) void aux_scan_kernel(float* __restrict__ aux2) {
    const int idx = blockIdx.x * 64 + threadIdx.x;    // 0..WC/4-1
    const int g   = idx / (HSTRIDE / 4);
    const int r4  = idx - g * (HSTRIDE / 4);
    float4* p = (float4*)aux2 + (size_t)g * (AUXG / 4) + r4;
    float4 acc = make_float4(0.f, 0.f, 0.f, 0.f);
    #pragma unroll
    for (int ch = 0; ch < NCHUNK; ++ch) {
        float4 v = p[(size_t)ch * (HSTRIDE / 4)];
        p[(size_t)ch * (HSTRIDE / 4)] = acc;
        acc.x += v.x; acc.y += v.y; acc.z += v.z; acc.w += v.w;
    }
}

// ----------------------------------------------------------------------------
// K4: pool8. Block = (box n, group g), blockIdx = n*8+g (XCD slicing).
//  - edges er/ec (28 ints) + 49 reciprocal areas precomputed once in LDS
//  - phase 1: 196 unique corner positions x 32ch loaded as float4 (8 lanes x
//    16 B -> one 128 B segment each), T2+aux summed, scattered to grid
//    (stride 33, scalar writes, ~2-way banks)
//  - phase 2: direct global store, no staging: flat = cg*49+i*7+j lane-
//    consecutive -> coalesced; value = (a-b-c+d) * rcpA[rem]
// LDS 26.2 KB -> 6 blocks/CU.
// ----------------------------------------------------------------------------
__global__ __launch_bounds__(256) void pool8_kernel(const float* __restrict__ T2,
                                                    const float* __restrict__ aux2,
                                                    const float* __restrict__ boxes,
                                                    float* __restrict__ out) {
    __shared__ float grid[196][GPAD];
    __shared__ int er[14];                 // rows: rs[0..6], re[0..6]
    __shared__ int ec[14];                 // cols: cs[0..6], ce[0..6]
    __shared__ float rcpA[49];
    const int bx = blockIdx.x;
    const int n  = bx >> 3;
    const int g  = bx & 7;
    const int t  = threadIdx.x;

    const float4 box = ((const float4*)boxes)[n];
    int b0 = (int)floorf(box.x * 0.25f);
    int b1 = (int)floorf(box.y * 0.25f);
    int b2 = (int)floorf(box.z * 0.25f);
    int b3 = (int)floorf(box.w * 0.25f);
    int x1 = min(max(b0, 0), W_FM - 1);
    int y1 = min(max(b1, 0), H_FM - 1);
    int x2 = min(max(b2 + 1, x1 + 1), W_FM);
    int y2 = min(max(b3 + 1, y1 + 1), H_FM);
    int rh = y2 - y1;
    int rw = x2 - x1;

    // ---- edge precompute
    if (t < 14) {
        er[t] = (t < 7) ? (y1 + (t * rh) / OHp)
                        : (y1 + ((t - 6) * rh + OHp - 1) / OHp);
    } else if (t >= 64 && t < 78) {
        int u = t - 64;
        ec[u] = (u < 7) ? (x1 + (u * rw) / OWp)
                        : (x1 + ((u - 6) * rw + OWp - 1) / OWp);
    }
    __syncthreads();

    // ---- 49 reciprocal areas (uses er/ec; published by the phase-1 barrier)
    if (t < 49) {
        int i = t / 7;
        int j = t - i * 7;
        rcpA[t] = 1.0f / (float)((er[7 + i] - er[i]) * (ec[7 + j] - ec[j]));
    }

    // ---- phase 1: grid load (positions deduped; edges from LDS)
    {
        const int c4 = t & 7;              // float4 slot within 32 channels
        const int p0 = t >> 3;             // 0..31 positions per iteration
        const float* Tg = T2   + (size_t)g * GSTRIDE + c4 * 4;
        const float* Ag = aux2 + (size_t)g * AUXG   + c4 * 4;
        #pragma unroll
        for (int it = 0; it < 7; ++it) {
            int pos = it * 32 + p0;
            if (pos < 196) {
                int ri = pos / 14;
                int ci = pos - ri * 14;
                int r = er[ri];
                int k = ec[ci];
                float4 v = make_float4(0.f, 0.f, 0.f, 0.f);
                if (r > 0 && k > 0) {
                    float4 tv = *(const float4*)(Tg + ((size_t)(r - 1) * W_FM + (k - 1)) * CG);
                    float4 av = *(const float4*)(Ag + ((size_t)((r - 1) >> 3) * W_FM + (k - 1)) * CG);
                    v.x = tv.x + av.x; v.y = tv.y + av.y;
                    v.z = tv.z + av.z; v.w = tv.w + av.w;
                }
                // scalar writes: banks (pos + 4*c4 + k) % 32 -> 2-way, free
                grid[pos][c4 * 4 + 0] = v.x;
                grid[pos][c4 * 4 + 1] = v.y;
                grid[pos][c4 * 4 + 2] = v.z;
                grid[pos][c4 * 4 + 3] = v.w;
            }
        }
    }
    __syncthreads();

    // ---- phase 2: compute + direct coalesced store
    float* dst = out + (size_t)n * (C_CH * 49) + (size_t)g * (CG * 49);
    #pragma unroll
    for (int k = 0; k < 7; ++k) {
        int flat = k * 256 + t;            // 0..1567
        if (flat < CG * 49) {
            int cg  = flat / 49;
            int rem = flat - cg * 49;
            int i = rem / 7;
            int j = rem - i * 7;
            float a = grid[(7 + i) * 14 + 7 + j][cg];   // II(re, ce)
            float b = grid[i * 14 + 7 + j][cg];         // II(rs, ce)
            float c = grid[(7 + i) * 14 + j][cg];       // II(re, cs)
            float d = grid[i * 14 + j][cg];             // II(rs, cs)
            dst[flat] = ((a - b) - (c - d)) * rcpA[rem];
        }
    }
}

// ============================================================================
// FALLBACK PATH — used only if workspace is too small.
// ============================================================================
__device__ __forceinline__ void box_edges(const float4 box, int i, int j,
                                          int& rs, int& re, int& cs, int& ce) {
    int b0 = (int)floorf(box.x * 0.25f);
    int b1 = (int)floorf(box.y * 0.25f);
    int b2 = (int)floorf(box.z * 0.25f);
    int b3 = (int)floorf(box.w * 0.25f);
    int x1 = min(max(b0, 0), W_FM - 1);
    int y1 = min(max(b1, 0), H_FM - 1);
    int x2 = min(max(b2 + 1, x1 + 1), W_FM);
    int y2 = min(max(b3 + 1, y1 + 1), H_FM);
    int rh = y2 - y1;
    int rw = x2 - x1;
    rs = y1 + (i * rh) / OHp;
    re = y1 + ((i + 1) * rh + OHp - 1) / OHp;
    cs = x1 + (j * rw) / OWp;
    ce = x1 + ((j + 1) * rw + OWp - 1) / OWp;
}

__global__ __launch_bounds__(256) void pool_direct_kernel(const float* __restrict__ fm,
                                                          const float* __restrict__ boxes,
                                                          float* __restrict__ out) {
    const int idx = blockIdx.x * 256 + threadIdx.x;
    const int j  = idx % OWp;
    const int t1 = idx / OWp;
    const int i  = t1 % OHp;
    const int t2 = t1 / OHp;
    const int c  = t2 % C_CH;
    const int n  = t2 / C_CH;

    const float4 box = ((const float4*)boxes)[n];
    int rs, re, cs, ce;
    box_edges(box, i, j, rs, re, cs, ce);

    const float* base = fm + (size_t)c * (H_FM * W_FM);
    float sum = 0.0f;
    for (int r = rs; r < re; ++r) {
        const float* rowp = base + (size_t)r * W_FM;
        for (int k = cs; k < ce; ++k) sum += rowp[k];
    }
    float area = (float)((re - rs) * (ce - cs));
    out[idx] = sum / area;
}

// ---------------------------------------------------------------------------
extern "C" void kernel_launch(void* const* d_in, const int* in_sizes, int n_in,
                              void* d_out, int out_size, void* d_ws, size_t ws_size,
                              hipStream_t stream) {
    const float* fm    = (const float*)d_in[0];   // [1,256,200,200] f32
    const float* boxes = (const float*)d_in[1];   // [1024,4] f32
    float* out = (float*)d_out;                   // [1024,256,7,7] f32

    const size_t tBytes   = (size_t)NG * GSTRIDE * sizeof(float);     // 40.96 MB
    const size_t auxBytes = (size_t)NG * AUXG * sizeof(float);        // 5.12 MB
    const int    total    = N_BOX * C_CH * OHp * OWp;
    const int    blocks   = total / 256;

    if (ws_size >= tBytes + auxBytes) {
        float* T2   = (float*)d_ws;
        float* aux2 = (float*)((char*)d_ws + tBytes);
        transpose_wscan_kernel<<<dim3(H_FM, NG), 256, 0, stream>>>(fm, T2);
        colscan_chunk_kernel<<<dim3(WC / 4 / 256, NCHUNK), 256, 0, stream>>>(T2, aux2);
        aux_scan_kernel<<<WC / 4 / 64, 64, 0, stream>>>(aux2);
        pool8_kernel<<<N_BOX * NG, 256, 0, stream>>>(T2, aux2, boxes, out);
    } else {
        pool_direct_kernel<<<blocks, 256, 0, stream>>>(fm, boxes, out);
    }
}